// Round 17
// baseline (75.082 us; speedup 1.0000x reference)
//
#include <hip/hip_runtime.h>
#include <hip/hip_bf16.h>

typedef _Float16 f16x8 __attribute__((ext_vector_type(8)));
typedef _Float16 f16x4 __attribute__((ext_vector_type(4)));
typedef float    f32x4 __attribute__((ext_vector_type(4)));

constexpr int BB = 4;
constexpr int CH = 128;
constexpr int PC = 64;
constexpr int NN = 4096;

// ---------------------------------------------------------------------------
// prefetch: contiguous grid-stride sweep of pos_bot (4 MB) + corr (8 MB) at
// full DRAM BW (~2-3 us) to pull them into L2/L3. proj's 64B/16KB-stride
// gathers then hit SRAM instead of paying a DRAM row-activate per 64 B
// (r15: proj warm = 11.9 us vs cold ~28 us -- this converts cold to warm).
// Runs every replay, so the harness's inter-replay fills can't leave us cold.
// ---------------------------------------------------------------------------
__global__ __launch_bounds__(256) void prefetch_kernel(
    const float* __restrict__ pos_bot,
    const float* __restrict__ corr,
    float*       __restrict__ sink)
{
    const size_t gid    = (size_t)blockIdx.x * 256 + threadIdx.x;
    const size_t stride = (size_t)gridDim.x * 256;
    float s = 0.f;

    const f32x4* p4 = reinterpret_cast<const f32x4*>(pos_bot);
    const size_t np = (size_t)BB * PC * NN / 4;
    for (size_t i = gid; i < np; i += stride) {
        f32x4 v = p4[i];
        s += v[0] + v[1] + v[2] + v[3];
    }
    const f32x4* c4 = reinterpret_cast<const f32x4*>(corr);
    const size_t nc = (size_t)BB * CH * NN / 4;
    for (size_t i = gid; i < nc; i += stride) {
        f32x4 v = c4[i];
        s += v[0] + v[1] + v[2] + v[3];
    }
    // keep the loads alive; condition is never true for real data
    if (s == 123456.789f) sink[0] = s;
}

// ---------------------------------------------------------------------------
// proj: r14 body verbatim (best measured: part of the 69.75 baseline).
// grid (N/16, 2*B); role = y>>2 (0: pos+sq, 1: val).
// ---------------------------------------------------------------------------
__global__ __launch_bounds__(256) void proj_kernel(
    const float* __restrict__ pos_bot,  // [B,64,N]
    const float* __restrict__ corr,     // [B,128,N]
    const float* __restrict__ Wp,       // [64,64]
    const float* __restrict__ bp,       // [64]
    const float* __restrict__ Wv,       // [128,128]
    const float* __restrict__ bv,       // [128]
    _Float16* __restrict__ xbuf,        // [B,N,64]
    float*    __restrict__ sq,          // [B,N]
    float*    __restrict__ eqF)         // [B,N,128]
{
    const int tid  = threadIdx.x;
    const int wid  = tid >> 6;
    const int lane = tid & 63;
    const int l15  = lane & 15;
    const int lg   = lane >> 4;
    const int b    = blockIdx.y & 3;
    const int n    = blockIdx.x * 16 + l15;

    if ((blockIdx.y >> 2) == 0) {
        const int mt = wid;
        f16x8 wf[2], pb[2];
#pragma unroll
        for (int ks = 0; ks < 2; ++ks) {
            const float* wp = Wp + (mt * 16 + l15) * PC + ks * 32 + lg * 8;
            f32x4 w0 = *reinterpret_cast<const f32x4*>(wp);
            f32x4 w1 = *reinterpret_cast<const f32x4*>(wp + 4);
            f16x8 f;
#pragma unroll
            for (int e = 0; e < 4; ++e) { f[e] = (_Float16)w0[e]; f[e + 4] = (_Float16)w1[e]; }
            wf[ks] = f;
            f16x8 g;
#pragma unroll
            for (int e = 0; e < 8; ++e) {
                const int c = ks * 32 + lg * 8 + e;
                g[e] = (_Float16)pos_bot[((size_t)(b * PC + c)) * NN + n];
            }
            pb[ks] = g;
        }

        f32x4 acc = {0.f, 0.f, 0.f, 0.f};
        acc = __builtin_amdgcn_mfma_f32_16x16x32_f16(wf[0], pb[0], acc, 0, 0, 0);
        acc = __builtin_amdgcn_mfma_f32_16x16x32_f16(wf[1], pb[1], acc, 0, 0, 0);

        float partial = 0.f;
        f16x4 h4;
#pragma unroll
        for (int r = 0; r < 4; ++r) {
            const int o = mt * 16 + lg * 4 + r;
            const float v = acc[r] + bp[o];
            const _Float16 h = (_Float16)v;
            h4[r] = h;
            const float hf = (float)h;
            partial = fmaf(hf, hf, partial);
        }
        *reinterpret_cast<f16x4*>(xbuf + ((size_t)(b * NN + n)) * PC + mt * 16 + lg * 4) = h4;

        partial += __shfl_xor(partial, 16);
        partial += __shfl_xor(partial, 32);
        __shared__ float psum[4][16];
        if (lane < 16) psum[wid][l15] = partial;
        __syncthreads();
        if (tid < 16)
            sq[b * NN + blockIdx.x * 16 + tid] =
                psum[0][tid] + psum[1][tid] + psum[2][tid] + psum[3][tid];
        return;
    }

    f16x8 cb[4];
#pragma unroll
    for (int ks = 0; ks < 4; ++ks) {
        f16x8 g;
#pragma unroll
        for (int e = 0; e < 8; ++e) {
            const int c = ks * 32 + lg * 8 + e;
            g[e] = (_Float16)corr[((size_t)(b * CH + c)) * NN + n];
        }
        cb[ks] = g;
    }
#pragma unroll
    for (int half = 0; half < 2; ++half) {
        const int ot = wid + half * 4;
        f32x4 acc = {0.f, 0.f, 0.f, 0.f};
#pragma unroll
        for (int ks = 0; ks < 4; ++ks) {
            const float* wv = Wv + (ot * 16 + l15) * CH + ks * 32 + lg * 8;
            f32x4 w0 = *reinterpret_cast<const f32x4*>(wv);
            f32x4 w1 = *reinterpret_cast<const f32x4*>(wv + 4);
            f16x8 f;
#pragma unroll
            for (int e = 0; e < 4; ++e) { f[e] = (_Float16)w0[e]; f[e + 4] = (_Float16)w1[e]; }
            acc = __builtin_amdgcn_mfma_f32_16x16x32_f16(f, cb[ks], acc, 0, 0, 0);
        }
        f32x4 o4;
#pragma unroll
        for (int r = 0; r < 4; ++r) o4[r] = acc[r] + bv[ot * 16 + lg * 4 + r];
        __builtin_nontemporal_store(
            o4, reinterpret_cast<f32x4*>(eqF + ((size_t)(b * NN + n)) * CH + ot * 16 + lg * 4));
    }
}

// ---------------------------------------------------------------------------
// gram: r14 single-generation version verbatim (measured at the ~6.9 TB/s
// write floor; ~37-40 us single pass -- r15 rep-5 dispatch = 5 x 37).
// ---------------------------------------------------------------------------
__global__ __launch_bounds__(256) void gram_kernel(
    const _Float16* __restrict__ xbuf,  // [B,N,64]
    const float*    __restrict__ sq,    // [B,N]
    const float*    __restrict__ beta,  // [1]
    float*          __restrict__ out)   // [B,N,N]
{
    const int tid  = threadIdx.x;
    const int wid  = tid >> 6;
    const int lane = tid & 63;
    const int l15  = lane & 15;
    const int lg   = lane >> 4;
    const int b    = blockIdx.z;
    const int jb   = blockIdx.x * 512;
    const int rb0  = blockIdx.y * 128;
    const int wjb  = jb + wid * 128;

    const _Float16* xb  = xbuf + (size_t)b * NN * PC;
    const float*    sqb = sq + (size_t)b * NN;

    const float bs   = -beta[0] * 1.44269504088896f;  // exp(-b*d2)=exp2(bs*d2)
    const float m2bs = -2.f * bs;

    f16x8 bf[8][2];
    float tj[8];
#pragma unroll
    for (int jtf = 0; jtf < 8; ++jtf) {
        const int j = wjb + jtf * 16 + l15;
#pragma unroll
        for (int ks = 0; ks < 2; ++ks)
            bf[jtf][ks] = *reinterpret_cast<const f16x8*>(
                xb + (size_t)j * PC + ks * 32 + lg * 8);
        tj[jtf] = bs * sqb[j];
    }

    __shared__ float lds[4][16][132];   // per-wave private quadrant

    for (int rbh = 0; rbh < 2; ++rbh) {
        const int rb = rb0 + rbh * 64;

        for (int sl = 0; sl < 4; ++sl) {
            const int ibase = rb + sl * 16;

            const f16x8 af0 = *reinterpret_cast<const f16x8*>(
                xb + (size_t)(ibase + l15) * PC + lg * 8);
            const f16x8 af1 = *reinterpret_cast<const f16x8*>(
                xb + (size_t)(ibase + l15) * PC + 32 + lg * 8);

            f32x4 acc[8];
#pragma unroll
            for (int jtf = 0; jtf < 8; ++jtf) {
                f32x4 z = {0.f, 0.f, 0.f, 0.f};
                acc[jtf] = __builtin_amdgcn_mfma_f32_16x16x32_f16(af0, bf[jtf][0], z, 0, 0, 0);
            }
#pragma unroll
            for (int jtf = 0; jtf < 8; ++jtf)
                acc[jtf] = __builtin_amdgcn_mfma_f32_16x16x32_f16(af1, bf[jtf][1], acc[jtf], 0, 0, 0);

            const f32x4 sv = *reinterpret_cast<const f32x4*>(sqb + ibase + lg * 4);

#pragma unroll
            for (int jtf = 0; jtf < 8; ++jtf) {
#pragma unroll
                for (int r = 0; r < 4; ++r) {
                    const float ti = bs * sv[r];
                    float arg = fminf(fmaf(m2bs, acc[jtf][r], ti + tj[jtf]), 0.f);
                    lds[wid][lg * 4 + r][jtf * 16 + l15] = __builtin_amdgcn_exp2f(arg);
                }
            }

#pragma unroll
            for (int k = 0; k < 8; ++k) {
                const int row = 2 * k + (lane >> 5);
                const int col = (lane & 31) * 4;
                const f32x4 v = *reinterpret_cast<const f32x4*>(&lds[wid][row][col]);
                __builtin_nontemporal_store(
                    v, reinterpret_cast<f32x4*>(
                           out + ((size_t)(b * NN + ibase + row)) * NN + wjb + col));
            }
        }
    }
}

extern "C" void kernel_launch(void* const* d_in, const int* in_sizes, int n_in,
                              void* d_out, int out_size, void* d_ws, size_t ws_size,
                              hipStream_t stream) {
    const float* pos_bot = (const float*)d_in[0];
    const float* corr    = (const float*)d_in[1];
    const float* Wp      = (const float*)d_in[2];
    const float* bp      = (const float*)d_in[3];
    const float* Wv      = (const float*)d_in[4];
    const float* bv      = (const float*)d_in[5];
    const float* beta    = (const float*)d_in[6];

    float* out = (float*)d_out;                       // kernel [B,N,N]
    float* eqF = out + (size_t)BB * NN * NN;          // equation_F [B,N,128]

    _Float16* xbuf = (_Float16*)d_ws;                 // 2 MB
    float* sq   = (float*)((char*)d_ws + (size_t)BB * NN * PC * sizeof(_Float16));
    float* sink = sq + (size_t)BB * NN;

    prefetch_kernel<<<dim3(1024), 256, 0, stream>>>(pos_bot, corr, sink);

    proj_kernel<<<dim3(NN / 16, 2 * BB), 256, 0, stream>>>(
        pos_bot, corr, Wp, bp, Wv, bv, xbuf, sq, eqF);

    gram_kernel<<<dim3(NN / 512, NN / 128, BB), 256, 0, stream>>>(
        xbuf, sq, beta, out);
}

// Round 19
// 71.022 us; speedup vs baseline: 1.0572x; 1.0572x over previous
//
#include <hip/hip_runtime.h>
#include <hip/hip_bf16.h>

typedef _Float16 f16x8 __attribute__((ext_vector_type(8)));
typedef _Float16 f16x4 __attribute__((ext_vector_type(4)));
typedef float    f32x4 __attribute__((ext_vector_type(4)));

constexpr int BB = 4;
constexpr int CH = 128;
constexpr int PC = 64;
constexpr int NN = 4096;

// ---------------------------------------------------------------------------
// proj: r14 body with ONE change -- eqF stores are now CACHED (plain) instead
// of NT. eqF's write pattern is 16 B/lane at 512 B row stride (sub-line
// scatter); NT bypassed L2 write-combining -> partial-line DRAM bursts with
// ~4x amplification + RMW (r7's lesson). Cached lets L2 assemble full 512 B
// rows from the wave's successive ot-stores before writeback.
// grid (N/16, 2*B); role = y>>2 (0: pos+sq, 1: val).
// ---------------------------------------------------------------------------
__global__ __launch_bounds__(256) void proj_kernel(
    const float* __restrict__ pos_bot,  // [B,64,N]
    const float* __restrict__ corr,     // [B,128,N]
    const float* __restrict__ Wp,       // [64,64]
    const float* __restrict__ bp,       // [64]
    const float* __restrict__ Wv,       // [128,128]
    const float* __restrict__ bv,       // [128]
    _Float16* __restrict__ xbuf,        // [B,N,64]
    float*    __restrict__ sq,          // [B,N]
    float*    __restrict__ eqF)         // [B,N,128]
{
    const int tid  = threadIdx.x;
    const int wid  = tid >> 6;
    const int lane = tid & 63;
    const int l15  = lane & 15;
    const int lg   = lane >> 4;
    const int b    = blockIdx.y & 3;
    const int n    = blockIdx.x * 16 + l15;

    if ((blockIdx.y >> 2) == 0) {
        const int mt = wid;
        f16x8 wf[2], pb[2];
#pragma unroll
        for (int ks = 0; ks < 2; ++ks) {
            const float* wp = Wp + (mt * 16 + l15) * PC + ks * 32 + lg * 8;
            f32x4 w0 = *reinterpret_cast<const f32x4*>(wp);
            f32x4 w1 = *reinterpret_cast<const f32x4*>(wp + 4);
            f16x8 f;
#pragma unroll
            for (int e = 0; e < 4; ++e) { f[e] = (_Float16)w0[e]; f[e + 4] = (_Float16)w1[e]; }
            wf[ks] = f;
            f16x8 g;
#pragma unroll
            for (int e = 0; e < 8; ++e) {
                const int c = ks * 32 + lg * 8 + e;
                g[e] = (_Float16)pos_bot[((size_t)(b * PC + c)) * NN + n];
            }
            pb[ks] = g;
        }

        f32x4 acc = {0.f, 0.f, 0.f, 0.f};
        acc = __builtin_amdgcn_mfma_f32_16x16x32_f16(wf[0], pb[0], acc, 0, 0, 0);
        acc = __builtin_amdgcn_mfma_f32_16x16x32_f16(wf[1], pb[1], acc, 0, 0, 0);

        float partial = 0.f;
        f16x4 h4;
#pragma unroll
        for (int r = 0; r < 4; ++r) {
            const int o = mt * 16 + lg * 4 + r;
            const float v = acc[r] + bp[o];
            const _Float16 h = (_Float16)v;
            h4[r] = h;
            const float hf = (float)h;
            partial = fmaf(hf, hf, partial);
        }
        *reinterpret_cast<f16x4*>(xbuf + ((size_t)(b * NN + n)) * PC + mt * 16 + lg * 4) = h4;

        partial += __shfl_xor(partial, 16);
        partial += __shfl_xor(partial, 32);
        __shared__ float psum[4][16];
        if (lane < 16) psum[wid][l15] = partial;
        __syncthreads();
        if (tid < 16)
            sq[b * NN + blockIdx.x * 16 + tid] =
                psum[0][tid] + psum[1][tid] + psum[2][tid] + psum[3][tid];
        return;
    }

    f16x8 cb[4];
#pragma unroll
    for (int ks = 0; ks < 4; ++ks) {
        f16x8 g;
#pragma unroll
        for (int e = 0; e < 8; ++e) {
            const int c = ks * 32 + lg * 8 + e;
            g[e] = (_Float16)corr[((size_t)(b * CH + c)) * NN + n];
        }
        cb[ks] = g;
    }
#pragma unroll
    for (int half = 0; half < 2; ++half) {
        const int ot = wid + half * 4;
        f32x4 acc = {0.f, 0.f, 0.f, 0.f};
#pragma unroll
        for (int ks = 0; ks < 4; ++ks) {
            const float* wv = Wv + (ot * 16 + l15) * CH + ks * 32 + lg * 8;
            f32x4 w0 = *reinterpret_cast<const f32x4*>(wv);
            f32x4 w1 = *reinterpret_cast<const f32x4*>(wv + 4);
            f16x8 f;
#pragma unroll
            for (int e = 0; e < 4; ++e) { f[e] = (_Float16)w0[e]; f[e + 4] = (_Float16)w1[e]; }
            acc = __builtin_amdgcn_mfma_f32_16x16x32_f16(f, cb[ks], acc, 0, 0, 0);
        }
        f32x4 o4;
#pragma unroll
        for (int r = 0; r < 4; ++r) o4[r] = acc[r] + bv[ot * 16 + lg * 4 + r];
        // CACHED store (was NT): 16 B/lane sub-line scatter must go through
        // L2 write-combining, not straight to DRAM.
        *reinterpret_cast<f32x4*>(eqF + ((size_t)(b * NN + n)) * CH + ot * 16 + lg * 4) = o4;
    }
}

// ---------------------------------------------------------------------------
// gram: r14 single-generation version verbatim (steady-state at the ~6.9
// TB/s write rate; NT stores here are full 512 B lines -- correct NT use,
// r6 A/B confirmed). 1024 blocks, block = 128i x 512j, bf prologue amortized
// over 2 row-strips, private-LDS transpose, zero main-loop barriers.
// ---------------------------------------------------------------------------
__global__ __launch_bounds__(256) void gram_kernel(
    const _Float16* __restrict__ xbuf,  // [B,N,64]
    const float*    __restrict__ sq,    // [B,N]
    const float*    __restrict__ beta,  // [1]
    float*          __restrict__ out)   // [B,N,N]
{
    const int tid  = threadIdx.x;
    const int wid  = tid >> 6;
    const int lane = tid & 63;
    const int l15  = lane & 15;
    const int lg   = lane >> 4;
    const int b    = blockIdx.z;
    const int jb   = blockIdx.x * 512;
    const int rb0  = blockIdx.y * 128;
    const int wjb  = jb + wid * 128;

    const _Float16* xb  = xbuf + (size_t)b * NN * PC;
    const float*    sqb = sq + (size_t)b * NN;

    const float bs   = -beta[0] * 1.44269504088896f;  // exp(-b*d2)=exp2(bs*d2)
    const float m2bs = -2.f * bs;

    f16x8 bf[8][2];
    float tj[8];
#pragma unroll
    for (int jtf = 0; jtf < 8; ++jtf) {
        const int j = wjb + jtf * 16 + l15;
#pragma unroll
        for (int ks = 0; ks < 2; ++ks)
            bf[jtf][ks] = *reinterpret_cast<const f16x8*>(
                xb + (size_t)j * PC + ks * 32 + lg * 8);
        tj[jtf] = bs * sqb[j];
    }

    __shared__ float lds[4][16][132];   // per-wave private quadrant

    for (int rbh = 0; rbh < 2; ++rbh) {
        const int rb = rb0 + rbh * 64;

        for (int sl = 0; sl < 4; ++sl) {
            const int ibase = rb + sl * 16;

            const f16x8 af0 = *reinterpret_cast<const f16x8*>(
                xb + (size_t)(ibase + l15) * PC + lg * 8);
            const f16x8 af1 = *reinterpret_cast<const f16x8*>(
                xb + (size_t)(ibase + l15) * PC + 32 + lg * 8);

            f32x4 acc[8];
#pragma unroll
            for (int jtf = 0; jtf < 8; ++jtf) {
                f32x4 z = {0.f, 0.f, 0.f, 0.f};
                acc[jtf] = __builtin_amdgcn_mfma_f32_16x16x32_f16(af0, bf[jtf][0], z, 0, 0, 0);
            }
#pragma unroll
            for (int jtf = 0; jtf < 8; ++jtf)
                acc[jtf] = __builtin_amdgcn_mfma_f32_16x16x32_f16(af1, bf[jtf][1], acc[jtf], 0, 0, 0);

            const f32x4 sv = *reinterpret_cast<const f32x4*>(sqb + ibase + lg * 4);

#pragma unroll
            for (int jtf = 0; jtf < 8; ++jtf) {
#pragma unroll
                for (int r = 0; r < 4; ++r) {
                    const float ti = bs * sv[r];
                    float arg = fminf(fmaf(m2bs, acc[jtf][r], ti + tj[jtf]), 0.f);
                    lds[wid][lg * 4 + r][jtf * 16 + l15] = __builtin_amdgcn_exp2f(arg);
                }
            }

#pragma unroll
            for (int k = 0; k < 8; ++k) {
                const int row = 2 * k + (lane >> 5);
                const int col = (lane & 31) * 4;
                const f32x4 v = *reinterpret_cast<const f32x4*>(&lds[wid][row][col]);
                __builtin_nontemporal_store(
                    v, reinterpret_cast<f32x4*>(
                           out + ((size_t)(b * NN + ibase + row)) * NN + wjb + col));
            }
        }
    }
}

extern "C" void kernel_launch(void* const* d_in, const int* in_sizes, int n_in,
                              void* d_out, int out_size, void* d_ws, size_t ws_size,
                              hipStream_t stream) {
    const float* pos_bot = (const float*)d_in[0];
    const float* corr    = (const float*)d_in[1];
    const float* Wp      = (const float*)d_in[2];
    const float* bp      = (const float*)d_in[3];
    const float* Wv      = (const float*)d_in[4];
    const float* bv      = (const float*)d_in[5];
    const float* beta    = (const float*)d_in[6];

    float* out = (float*)d_out;                       // kernel [B,N,N]
    float* eqF = out + (size_t)BB * NN * NN;          // equation_F [B,N,128]

    _Float16* xbuf = (_Float16*)d_ws;                 // 2 MB
    float* sq = (float*)((char*)d_ws + (size_t)BB * NN * PC * sizeof(_Float16));

    proj_kernel<<<dim3(NN / 16, 2 * BB), 256, 0, stream>>>(
        pos_bot, corr, Wp, bp, Wv, bv, xbuf, sq, eqF);

    gram_kernel<<<dim3(NN / 512, NN / 128, BB), 256, 0, stream>>>(
        xbuf, sq, beta, out);
}

// Round 20
// 70.117 us; speedup vs baseline: 1.0708x; 1.0129x over previous
//
#include <hip/hip_runtime.h>
#include <hip/hip_bf16.h>

typedef _Float16 f16x8 __attribute__((ext_vector_type(8)));
typedef _Float16 f16x4 __attribute__((ext_vector_type(4)));
typedef float    f32x4 __attribute__((ext_vector_type(4)));

constexpr int BB = 4;
constexpr int CH = 128;
constexpr int PC = 64;
constexpr int NN = 4096;

// ---------------------------------------------------------------------------
// FINAL (champion = round 14, 69.75 us).
// Decomposition (all measured):
//   proj ~12 us  (latency-bound gather+MFMA; staging/prefetch/store-policy
//                 variants all regressed: r16/r17/r19)
//   gram ~39 us  (268 MB NT writes at 6.85 TB/s = the write floor; proven by
//                 rep-loop marginals r12/r15 == harness fill calibration)
//   ~19 us       (2x launch overhead + cold pass; single-launch fusion blocked
//                 by XCD coherence: r13 queue = 4x BW collapse, r9 recompute
//                 = +31 us serial chains, r18 cooperative = capture-fail)
// proj: grid (N/16, 2*B); role = y>>2 (0: pos-proj + sq, 1: val-proj).
// ---------------------------------------------------------------------------
__global__ __launch_bounds__(256) void proj_kernel(
    const float* __restrict__ pos_bot,  // [B,64,N]
    const float* __restrict__ corr,     // [B,128,N]
    const float* __restrict__ Wp,       // [64,64]
    const float* __restrict__ bp,       // [64]
    const float* __restrict__ Wv,       // [128,128]
    const float* __restrict__ bv,       // [128]
    _Float16* __restrict__ xbuf,        // [B,N,64]
    float*    __restrict__ sq,          // [B,N]
    float*    __restrict__ eqF)         // [B,N,128]
{
    const int tid  = threadIdx.x;
    const int wid  = tid >> 6;
    const int lane = tid & 63;
    const int l15  = lane & 15;
    const int lg   = lane >> 4;
    const int b    = blockIdx.y & 3;
    const int n    = blockIdx.x * 16 + l15;

    if ((blockIdx.y >> 2) == 0) {
        // ---- pos projection: x~ = f16(Wp @ pos_bot + bp), sq = ||x~||^2 ----
        const int mt = wid;
        f16x8 wf[2], pb[2];
#pragma unroll
        for (int ks = 0; ks < 2; ++ks) {
            const float* wp = Wp + (mt * 16 + l15) * PC + ks * 32 + lg * 8;
            f32x4 w0 = *reinterpret_cast<const f32x4*>(wp);
            f32x4 w1 = *reinterpret_cast<const f32x4*>(wp + 4);
            f16x8 f;
#pragma unroll
            for (int e = 0; e < 4; ++e) { f[e] = (_Float16)w0[e]; f[e + 4] = (_Float16)w1[e]; }
            wf[ks] = f;
            f16x8 g;
#pragma unroll
            for (int e = 0; e < 8; ++e) {
                const int c = ks * 32 + lg * 8 + e;
                g[e] = (_Float16)pos_bot[((size_t)(b * PC + c)) * NN + n];
            }
            pb[ks] = g;
        }

        f32x4 acc = {0.f, 0.f, 0.f, 0.f};
        acc = __builtin_amdgcn_mfma_f32_16x16x32_f16(wf[0], pb[0], acc, 0, 0, 0);
        acc = __builtin_amdgcn_mfma_f32_16x16x32_f16(wf[1], pb[1], acc, 0, 0, 0);

        float partial = 0.f;
        f16x4 h4;
#pragma unroll
        for (int r = 0; r < 4; ++r) {
            const int o = mt * 16 + lg * 4 + r;
            const float v = acc[r] + bp[o];
            const _Float16 h = (_Float16)v;
            h4[r] = h;
            const float hf = (float)h;
            partial = fmaf(hf, hf, partial);
        }
        *reinterpret_cast<f16x4*>(xbuf + ((size_t)(b * NN + n)) * PC + mt * 16 + lg * 4) = h4;

        partial += __shfl_xor(partial, 16);
        partial += __shfl_xor(partial, 32);
        __shared__ float psum[4][16];
        if (lane < 16) psum[wid][l15] = partial;
        __syncthreads();
        if (tid < 16)
            sq[b * NN + blockIdx.x * 16 + tid] =
                psum[0][tid] + psum[1][tid] + psum[2][tid] + psum[3][tid];
        return;
    }

    // ---- value projection: eqF = Wv @ corr + bv ----
    f16x8 cb[4];
#pragma unroll
    for (int ks = 0; ks < 4; ++ks) {
        f16x8 g;
#pragma unroll
        for (int e = 0; e < 8; ++e) {
            const int c = ks * 32 + lg * 8 + e;
            g[e] = (_Float16)corr[((size_t)(b * CH + c)) * NN + n];
        }
        cb[ks] = g;
    }
#pragma unroll
    for (int half = 0; half < 2; ++half) {
        const int ot = wid + half * 4;
        f32x4 acc = {0.f, 0.f, 0.f, 0.f};
#pragma unroll
        for (int ks = 0; ks < 4; ++ks) {
            const float* wv = Wv + (ot * 16 + l15) * CH + ks * 32 + lg * 8;
            f32x4 w0 = *reinterpret_cast<const f32x4*>(wv);
            f32x4 w1 = *reinterpret_cast<const f32x4*>(wv + 4);
            f16x8 f;
#pragma unroll
            for (int e = 0; e < 4; ++e) { f[e] = (_Float16)w0[e]; f[e + 4] = (_Float16)w1[e]; }
            acc = __builtin_amdgcn_mfma_f32_16x16x32_f16(f, cb[ks], acc, 0, 0, 0);
        }
        f32x4 o4;
#pragma unroll
        for (int r = 0; r < 4; ++r) o4[r] = acc[r] + bv[ot * 16 + lg * 4 + r];
        __builtin_nontemporal_store(
            o4, reinterpret_cast<f32x4*>(eqF + ((size_t)(b * NN + n)) * CH + ot * 16 + lg * 4));
    }
}

// ---------------------------------------------------------------------------
// gram: single-generation (1024 blocks = exactly 4/CU), block = 128i x 512j,
// bf prologue loaded once and amortized over 2 row-strips x 4 slices.
// Per slice: 16 MFMA -> exp2 -> private-LDS transpose (per-wave quadrant,
// zero cross-wave barriers) -> 512 B-contiguous full-line NT stores.
// Steady state measured at 6.85 TB/s == the DRAM write floor (r12/r15).
// MFMA layout (verified): acc=mfma(af,bf): i = lg*4+r, j = jtf*16+l15.
// ---------------------------------------------------------------------------
__global__ __launch_bounds__(256) void gram_kernel(
    const _Float16* __restrict__ xbuf,  // [B,N,64]
    const float*    __restrict__ sq,    // [B,N]
    const float*    __restrict__ beta,  // [1]
    float*          __restrict__ out)   // [B,N,N]
{
    const int tid  = threadIdx.x;
    const int wid  = tid >> 6;
    const int lane = tid & 63;
    const int l15  = lane & 15;
    const int lg   = lane >> 4;
    const int b    = blockIdx.z;
    const int jb   = blockIdx.x * 512;
    const int rb0  = blockIdx.y * 128;
    const int wjb  = jb + wid * 128;

    const _Float16* xb  = xbuf + (size_t)b * NN * PC;
    const float*    sqb = sq + (size_t)b * NN;

    const float bs   = -beta[0] * 1.44269504088896f;  // exp(-b*d2)=exp2(bs*d2)
    const float m2bs = -2.f * bs;

    f16x8 bf[8][2];
    float tj[8];
#pragma unroll
    for (int jtf = 0; jtf < 8; ++jtf) {
        const int j = wjb + jtf * 16 + l15;
#pragma unroll
        for (int ks = 0; ks < 2; ++ks)
            bf[jtf][ks] = *reinterpret_cast<const f16x8*>(
                xb + (size_t)j * PC + ks * 32 + lg * 8);
        tj[jtf] = bs * sqb[j];
    }

    __shared__ float lds[4][16][132];   // per-wave private quadrant

    for (int rbh = 0; rbh < 2; ++rbh) {
        const int rb = rb0 + rbh * 64;

        for (int sl = 0; sl < 4; ++sl) {
            const int ibase = rb + sl * 16;

            const f16x8 af0 = *reinterpret_cast<const f16x8*>(
                xb + (size_t)(ibase + l15) * PC + lg * 8);
            const f16x8 af1 = *reinterpret_cast<const f16x8*>(
                xb + (size_t)(ibase + l15) * PC + 32 + lg * 8);

            f32x4 acc[8];
#pragma unroll
            for (int jtf = 0; jtf < 8; ++jtf) {
                f32x4 z = {0.f, 0.f, 0.f, 0.f};
                acc[jtf] = __builtin_amdgcn_mfma_f32_16x16x32_f16(af0, bf[jtf][0], z, 0, 0, 0);
            }
#pragma unroll
            for (int jtf = 0; jtf < 8; ++jtf)
                acc[jtf] = __builtin_amdgcn_mfma_f32_16x16x32_f16(af1, bf[jtf][1], acc[jtf], 0, 0, 0);

            const f32x4 sv = *reinterpret_cast<const f32x4*>(sqb + ibase + lg * 4);

#pragma unroll
            for (int jtf = 0; jtf < 8; ++jtf) {
#pragma unroll
                for (int r = 0; r < 4; ++r) {
                    const float ti = bs * sv[r];
                    float arg = fminf(fmaf(m2bs, acc[jtf][r], ti + tj[jtf]), 0.f);
                    lds[wid][lg * 4 + r][jtf * 16 + l15] = __builtin_amdgcn_exp2f(arg);
                }
            }

#pragma unroll
            for (int k = 0; k < 8; ++k) {
                const int row = 2 * k + (lane >> 5);
                const int col = (lane & 31) * 4;
                const f32x4 v = *reinterpret_cast<const f32x4*>(&lds[wid][row][col]);
                __builtin_nontemporal_store(
                    v, reinterpret_cast<f32x4*>(
                           out + ((size_t)(b * NN + ibase + row)) * NN + wjb + col));
            }
        }
    }
}

extern "C" void kernel_launch(void* const* d_in, const int* in_sizes, int n_in,
                              void* d_out, int out_size, void* d_ws, size_t ws_size,
                              hipStream_t stream) {
    const float* pos_bot = (const float*)d_in[0];
    const float* corr    = (const float*)d_in[1];
    const float* Wp      = (const float*)d_in[2];
    const float* bp      = (const float*)d_in[3];
    const float* Wv      = (const float*)d_in[4];
    const float* bv      = (const float*)d_in[5];
    const float* beta    = (const float*)d_in[6];

    float* out = (float*)d_out;                       // kernel [B,N,N]
    float* eqF = out + (size_t)BB * NN * NN;          // equation_F [B,N,128]

    _Float16* xbuf = (_Float16*)d_ws;                 // 2 MB
    float* sq = (float*)((char*)d_ws + (size_t)BB * NN * PC * sizeof(_Float16));

    proj_kernel<<<dim3(NN / 16, 2 * BB), 256, 0, stream>>>(
        pos_bot, corr, Wp, bp, Wv, bv, xbuf, sq, eqF);

    gram_kernel<<<dim3(NN / 512, NN / 128, BB), 256, 0, stream>>>(
        xbuf, sq, beta, out);
}